// Round 11
// baseline (154.527 us; speedup 1.0000x reference)
//
#include <hip/hip_runtime.h>
#include <hip/hip_bf16.h>
#include <hip/hip_cooperative_groups.h>

namespace cg = cooperative_groups;

// ---------------------------------------------------------------------------
// Metric_Loss: two fused (X X^T/128 -> exp(1+.) -> row-sum) passes + pair combine.
// B=8192, E=128, P=4096.  Output: scalar f32 = metric_tt + metric_st.
//
// Round 11: cooperative fusion, robust. Single fused kernel with grid=512
// (2 blocks/CU -- far under cooperative occupancy limits), phases as
// grid-stride loops over the same logical work as R8 (2048 gemm groups,
// NH=8, MX-fp8 16x16x128, 2-phase counted-vmcnt). Return code checked:
// on failure falls back to the known-good R8 three-kernel pipeline.
//
// ws layout:
//   [0, 1MB)        Xt fp8    [8192][128]   scaled by sqrt(log2e/128)
//   [1MB, 2MB)      Xm fp8    [8192][128]   (mixed: even=text, odd=shape[r>>1])
//   [2MB, 2MB+64KB) R f32     [2][8192]     row sums of exp(1+D)
// ---------------------------------------------------------------------------

#define B_ROWS 8192
#define E_COLS 128
#define P_PAIRS 4096
#define NSTRIP 128              // 64-row strips
#define NH 8                    // h-splits per strip
#define NGROUP 2048             // 128 strips x 8 splits x 2 layers

using f32x4 = __attribute__((ext_vector_type(4))) float;
using i32x8 = __attribute__((ext_vector_type(8))) int;

// sqrt(log2(e)/128): MFMA yields acc = D*log2(e); exp(1+D) = e * exp2(acc)
#define BF_SCALE 0.106164482742544f
#define EULER    2.718281828459045f
#define SCALE1   0x7f            // E8M0 exponent 127 -> 2^0 (unit scale)

__device__ __forceinline__ unsigned pk4_fp8(float a, float b, float c, float d) {
    unsigned v = 0;
    v = __builtin_amdgcn_cvt_pk_fp8_f32(a * BF_SCALE, b * BF_SCALE, v, false);
    v = __builtin_amdgcn_cvt_pk_fp8_f32(c * BF_SCALE, d * BF_SCALE, v, true);
    return v;
}

__device__ __forceinline__ int lds_off(int row, int k0) {
    return (row << 7) + (k0 ^ ((row & 7) << 4));
}

// K=128 fragment from swizzled LDS: 32 contiguous fp8 at (row, k32).
__device__ __forceinline__ i32x8 load_frag32(const char* base, int row, int k32) {
    union { i32x8 v; int4 h[2]; } u;
    u.h[0] = *(const int4*)(base + lds_off(row, k32));
    u.h[1] = *(const int4*)(base + lds_off(row, k32 + 16));
    return u.v;
}

// Stage one 64x128 fp8 tile (8KB): 2 iters of 256 threads x 16B.
__device__ __forceinline__ void stage8k(const char* gsrc, char* ldst, int tid) {
#pragma unroll
    for (int it = 0; it < 2; ++it) {
        int L   = it * 4096 + tid * 16;
        int row = L >> 7;
        int cb  = L & 127;
        int src = (row << 7) + (cb ^ ((row & 7) << 4));
        __builtin_amdgcn_global_load_lds(
            (const __attribute__((address_space(1))) void*)(gsrc + src),
            (__attribute__((address_space(3))) void*)(ldst + L), 16, 0, 0);
    }
}

// ---------------- shared bodies (used by fused AND fallback kernels) -------

__device__ __forceinline__ void convert_item(int idx,
                                             const float* __restrict__ text,
                                             const float* __restrict__ shape,
                                             unsigned* __restrict__ Xt,
                                             unsigned* __restrict__ Xm,
                                             float* __restrict__ R,
                                             float* __restrict__ out) {
    if (idx < 4096) {                            // zero R (2*8192 f32)
        float4 z; z.x = z.y = z.z = z.w = 0.f;
        ((float4*)R)[idx] = z;
    }
    if (idx == 0) *out = 0.f;
    int e = idx * 4;
    float4 t = *(const float4*)(text + e);
    unsigned tp = pk4_fp8(t.x, t.y, t.z, t.w);
    Xt[idx] = tp;
    int row = e >> 7;
    if (row & 1) {
        int col = e & 127;
        float4 s = *(const float4*)(shape + (row >> 1) * E_COLS + col);
        Xm[idx] = pk4_fp8(s.x, s.y, s.z, s.w);
    } else {
        Xm[idx] = tp;
    }
}

// One gemm group = R8's per-block work: strip bm, split h, layer l.
__device__ __forceinline__ void gemm_group_body(const char* __restrict__ gX,
                                                float* __restrict__ R,
                                                int bm, int h, int l, int tid,
                                                char* buf0, char* buf1) {
    const int t0 = (h == 0) ? NH : h;
    const int N  = (h == 0) ? (bm < 64 ? 8 : 7) : 8;     // off-diag tile count

    // ---- prologue: stage A -> buf0, first B -> buf1 ----
    stage8k(gX + (size_t)bm * 8192, buf0, tid);
    stage8k(gX + (size_t)((bm + t0) & 127) * 8192, buf1, tid);
    asm volatile("s_waitcnt vmcnt(2)" ::: "memory");     // A landed
    __builtin_amdgcn_s_barrier();

    const int lane = tid & 63;
    const int w  = tid >> 6;
    const int wr = w >> 1, wc = w & 1;
    const int rA0 = wr * 32 + (lane & 15);
    const int rB0 = wc * 32 + (lane & 15);
    const int k32 = (lane >> 4) * 32;            // byte offset of lane's K-slice

    // ---- hoist A fragments (2 m-frags, full K=128 each) ----
    i32x8 afr[2];
#pragma unroll
    for (int m = 0; m < 2; ++m)
        afr[m] = load_frag32(buf0, rA0 + m * 16, k32);

    float s_r[2][4] = {{0.f}};                   // persistent row partials [m][j]

    // ---- diagonal tile (h==0): B-frags also from buf0; rows only ----
    if (h == 0) {
        i32x8 bfr[2];
#pragma unroll
        for (int n = 0; n < 2; ++n)
            bfr[n] = load_frag32(buf0, rB0 + n * 16, k32);
        f32x4 acc[2][2] = {};
#pragma unroll
        for (int m = 0; m < 2; ++m)
#pragma unroll
            for (int n = 0; n < 2; ++n)
                acc[m][n] = __builtin_amdgcn_mfma_scale_f32_16x16x128_f8f6f4(
                    afr[m], bfr[n], acc[m][n], 0, 0, 0, SCALE1, 0, SCALE1);
#pragma unroll
        for (int m = 0; m < 2; ++m)
#pragma unroll
            for (int n = 0; n < 2; ++n)
#pragma unroll
                for (int j = 0; j < 4; ++j)
                    s_r[m][j] += __builtin_amdgcn_exp2f(acc[m][n][j]);
    }

    // ---- all buf0 reads done before it becomes a B buffer ----
    asm volatile("s_waitcnt lgkmcnt(0)" ::: "memory");
    __builtin_amdgcn_s_barrier();

    // ---- 2-phase pipelined loop over off-diagonal tiles ----
    int cur = 1;                                 // current B buffer: 1 -> buf1
    for (int idx = 0; idx < N; ++idx) {
        const bool hasnext = (idx + 1 < N);
        if (hasnext)
            stage8k(gX + (size_t)((bm + t0 + NH * (idx + 1)) & 127) * 8192,
                    cur ? buf0 : buf1, tid);

        if (hasnext) { asm volatile("s_waitcnt vmcnt(2)" ::: "memory"); }
        else         { asm volatile("s_waitcnt vmcnt(0)" ::: "memory"); }
        __builtin_amdgcn_s_barrier();            // cur buffer staged (all waves)

        const char* lsrc = cur ? buf1 : buf0;
        i32x8 bfr[2];
#pragma unroll
        for (int n = 0; n < 2; ++n)
            bfr[n] = load_frag32(lsrc, rB0 + n * 16, k32);
        f32x4 acc[2][2] = {};
#pragma unroll
        for (int m = 0; m < 2; ++m)
#pragma unroll
            for (int n = 0; n < 2; ++n)
                acc[m][n] = __builtin_amdgcn_mfma_scale_f32_16x16x128_f8f6f4(
                    afr[m], bfr[n], acc[m][n], 0, 0, 0, SCALE1, 0, SCALE1);

        asm volatile("s_waitcnt lgkmcnt(0)" ::: "memory");
        __builtin_amdgcn_s_barrier();            // cur reads done -> overwritable

        // ---- epilogue: rows -> regs, cols -> shuffle + atomics ----
        const int bn = (bm + t0 + NH * idx) & 127;
        float s_c[2] = {0.f, 0.f};
#pragma unroll
        for (int m = 0; m < 2; ++m)
#pragma unroll
            for (int n = 0; n < 2; ++n)
#pragma unroll
                for (int j = 0; j < 4; ++j) {
                    float e2 = __builtin_amdgcn_exp2f(acc[m][n][j]);
                    s_r[m][j] += e2;
                    s_c[n] += e2;
                }
#pragma unroll
        for (int n = 0; n < 2; ++n) {
            float v = s_c[n];
            v += __shfl_xor(v, 16, 64);
            v += __shfl_xor(v, 32, 64);
            if (lane < 16) {
                int gcol = bn * 64 + wc * 32 + n * 16 + lane;
                atomicAdd(&R[l * B_ROWS + gcol], EULER * v);
            }
        }
        cur ^= 1;
    }

    // ---- final row reduction (once per group) ----
#pragma unroll
    for (int m = 0; m < 2; ++m)
#pragma unroll
        for (int j = 0; j < 4; ++j) {
            float v = s_r[m][j];
            v += __shfl_xor(v, 1, 64);
            v += __shfl_xor(v, 2, 64);
            v += __shfl_xor(v, 4, 64);
            v += __shfl_xor(v, 8, 64);
            if ((lane & 15) == 0) {
                int grow = bm * 64 + wr * 32 + m * 16 + (lane >> 4) * 4 + j;
                atomicAdd(&R[l * B_ROWS + grow], EULER * v);
            }
        }
}

__device__ __forceinline__ float finalize_task(int task,
                                               const float* __restrict__ text,
                                               const float* __restrict__ shape,
                                               const float* __restrict__ R,
                                               int lane) {
    const float inv128 = 0.0078125f;
    int l = task >> 12;
    int p = task & (P_PAIRS - 1);
    const float* a = text + (2 * p) * E_COLS;                // even row: text
    const float* b = l ? (shape + p * E_COLS) : (text + (2 * p + 1) * E_COLS);
    float2 av = *(const float2*)(a + lane * 2);
    float2 bv = *(const float2*)(b + lane * 2);
    float dii = av.x * av.x + av.y * av.y;
    float djj = bv.x * bv.x + bv.y * bv.y;
    float dij = av.x * bv.x + av.y * bv.y;
#pragma unroll
    for (int sh = 1; sh < 64; sh <<= 1) {
        dii += __shfl_xor(dii, sh, 64);
        djj += __shfl_xor(djj, sh, 64);
        dij += __shfl_xor(dij, sh, 64);
    }
    float r = 0.f;
    if (lane == 0) {
        float Dii = dii * inv128, Djj = djj * inv128, Dij = dij * inv128;
        float S = R[l * B_ROWS + 2 * p] + R[l * B_ROWS + 2 * p + 1]
                - (__expf(1.f + Dii) + 2.f * __expf(1.f + Dij) + __expf(1.f + Djj));
        float J = __logf(S) - Dij;
        r = 0.5f * J * J * (1.0f / (float)P_PAIRS);
    }
    return r;
}

// ---------------- fused cooperative kernel (grid = 512) --------------------
__launch_bounds__(256, 4)
__global__ void fused_kernel(const float* __restrict__ text,
                             const float* __restrict__ shape,
                             unsigned char* __restrict__ Xt8,
                             unsigned char* __restrict__ Xm8,
                             float* __restrict__ R,
                             float* __restrict__ out) {
    cg::grid_group grid = cg::this_grid();
    const int tid = threadIdx.x;
    const int bid = blockIdx.x;
    const int nb  = gridDim.x;

    __shared__ __align__(16) char buf0[64 * 128];
    __shared__ __align__(16) char buf1[64 * 128];
    __shared__ float red[4];

    // phase 0: convert (grid-stride over 262144 dwords)
    for (int idx = bid * 256 + tid; idx < B_ROWS * E_COLS / 4; idx += nb * 256)
        convert_item(idx, text, shape, (unsigned*)Xt8, (unsigned*)Xm8, R, out);
    grid.sync();

    // phase 1: gemm+rowsum (grid-stride over 2048 groups)
    for (int g = bid; g < NGROUP; g += nb) {
        const int bm = g & 127;
        const int h  = (g >> 7) & 7;
        const int l  = g >> 10;
        gemm_group_body((const char*)(l ? Xm8 : Xt8), R, bm, h, l, tid, buf0, buf1);
        __syncthreads();
    }
    grid.sync();

    // phase 2: finalize (grid-stride over 8192 pair-tasks, one per wave)
    {
        const int lane = tid & 63;
        const int w = tid >> 6;
        float accum = 0.f;
        for (int task = bid * 4 + w; task < 2 * P_PAIRS; task += nb * 4)
            accum += finalize_task(task, text, shape, R, lane);
        if (lane == 0) red[w] = accum;
        __syncthreads();
        if (tid == 0) atomicAdd(out, red[0] + red[1] + red[2] + red[3]);
    }
}

// ---------------- fallback kernels (R8 pipeline) ---------------------------
__global__ void convert_kernel(const float* __restrict__ text,
                               const float* __restrict__ shape,
                               unsigned* __restrict__ Xt,
                               unsigned* __restrict__ Xm,
                               float* __restrict__ R,
                               float* __restrict__ out) {
    int idx = blockIdx.x * blockDim.x + threadIdx.x;
    if (idx < B_ROWS * E_COLS / 4)
        convert_item(idx, text, shape, Xt, Xm, R, out);
}

__launch_bounds__(256, 4)
__global__ void gemm_rowsum_kernel(const unsigned char* __restrict__ Xt,
                                   const unsigned char* __restrict__ Xm,
                                   float* __restrict__ R) {
    __shared__ __align__(16) char buf0[64 * 128];
    __shared__ __align__(16) char buf1[64 * 128];
    const int bm = blockIdx.x, h = blockIdx.y, l = blockIdx.z;
    gemm_group_body((const char*)(l ? Xm : Xt), R, bm, h, l, threadIdx.x,
                    buf0, buf1);
}

__global__ void finalize_kernel(const float* __restrict__ text,
                                const float* __restrict__ shape,
                                const float* __restrict__ R,
                                float* __restrict__ out) {
    const int tid = threadIdx.x;
    const int lane = tid & 63;
    const int w = tid >> 6;
    float accum = 0.f;
    for (int task = blockIdx.x * 4 + w; task < 2 * P_PAIRS; task += 1024)
        accum += finalize_task(task, text, shape, R, lane);
    __shared__ float red[4];
    if (lane == 0) red[w] = accum;
    __syncthreads();
    if (tid == 0) atomicAdd(out, red[0] + red[1] + red[2] + red[3]);
}

// --------------------------- launch ----------------------------------------
extern "C" void kernel_launch(void* const* d_in, const int* in_sizes, int n_in,
                              void* d_out, int out_size, void* d_ws, size_t ws_size,
                              hipStream_t stream) {
    const float* text  = (const float*)d_in[0];
    const float* shape = (const float*)d_in[1];
    float* out = (float*)d_out;
    char* ws = (char*)d_ws;

    unsigned char* Xt = (unsigned char*)ws;
    unsigned char* Xm = (unsigned char*)(ws + 1u * 1024u * 1024u);
    float* R = (float*)(ws + 2u * 1024u * 1024u);

    void* kargs[] = {(void*)&text, (void*)&shape, (void*)&Xt, (void*)&Xm,
                     (void*)&R, (void*)&out};
    hipError_t err = hipLaunchCooperativeKernel((const void*)fused_kernel,
                                                dim3(512), dim3(256),
                                                kargs, 0, stream);
    if (err != hipSuccess) {
        (void)hipGetLastError();                 // clear sticky error
        convert_kernel<<<(B_ROWS * E_COLS / 4 + 255) / 256, 256, 0, stream>>>(
            text, shape, (unsigned*)Xt, (unsigned*)Xm, R, out);
        gemm_rowsum_kernel<<<dim3(NSTRIP, NH, 2), 256, 0, stream>>>(Xt, Xm, R);
        finalize_kernel<<<256, 256, 0, stream>>>(text, shape, R, out);
    }
}

// Round 12
// 48.281 us; speedup vs baseline: 3.2006x; 3.2006x over previous
//
#include <hip/hip_runtime.h>
#include <hip/hip_bf16.h>

// ---------------------------------------------------------------------------
// Metric_Loss: two fused (X X^T/128 -> exp(1+.) -> row-sum) passes + pair combine.
// B=8192, E=128, P=4096.  Output: scalar f32 = metric_tt + metric_st.
//
// Round 12: latency-attack on the gemm (R11 proved it latency-bound:
// throughput ~linear in resident waves; envelope ~15us fixed).
//  - pair-tiles: 2 tiles per iteration, ONE s_barrier per pair
//  - ring-3 banks (6 x 8KB LDS = 48KB): stage pair k+2 while consuming pair k
//    -> ~2 iterations (>1500 cyc) between stage issue and consumption
//  - A-frags + diagonal tile read straight from global (L2-hot, no A buffer)
//  - col-sum shuffles+atomics DEFERRED out of the loop (clean vmcnt counting,
//    shorter barrier-to-barrier chain); fully unrolled 8-tile loop (static
//    register indexing); uniform trip count via gate on the redundant tile
//  - MX-fp8 16x16x128 MFMA, exp2 pre-scale sqrt(log2e/128) as R8
//
// ws layout:
//   [0, 1MB)        Xt fp8    [8192][128]   scaled by sqrt(log2e/128)
//   [1MB, 2MB)      Xm fp8    [8192][128]   (mixed: even=text, odd=shape[r>>1])
//   [2MB, 2MB+64KB) R f32     [2][8192]     row sums of exp(1+D)
// ---------------------------------------------------------------------------

#define B_ROWS 8192
#define E_COLS 128
#define P_PAIRS 4096
#define NSTRIP 128              // 64-row strips
#define NH 8                    // h-splits per strip

using f32x4 = __attribute__((ext_vector_type(4))) float;
using i32x8 = __attribute__((ext_vector_type(8))) int;

// sqrt(log2(e)/128): MFMA yields acc = D*log2(e); exp(1+D) = e * exp2(acc)
#define BF_SCALE 0.106164482742544f
#define EULER    2.718281828459045f
#define SCALE1   0x7f            // E8M0 exponent 127 -> 2^0 (unit scale)

__device__ __forceinline__ unsigned pk4_fp8(float a, float b, float c, float d) {
    unsigned v = 0;
    v = __builtin_amdgcn_cvt_pk_fp8_f32(a * BF_SCALE, b * BF_SCALE, v, false);
    v = __builtin_amdgcn_cvt_pk_fp8_f32(c * BF_SCALE, d * BF_SCALE, v, true);
    return v;
}

__device__ __forceinline__ int lds_off(int row, int k0) {
    return (row << 7) + (k0 ^ ((row & 7) << 4));
}

// K=128 fragment from swizzled LDS: 32 contiguous fp8 at (row, k32).
__device__ __forceinline__ i32x8 load_frag32(const char* base, int row, int k32) {
    union { i32x8 v; int4 h[2]; } u;
    u.h[0] = *(const int4*)(base + lds_off(row, k32));
    u.h[1] = *(const int4*)(base + lds_off(row, k32 + 16));
    return u.v;
}

// K=128 fragment straight from global (row-major, unswizzled).
__device__ __forceinline__ i32x8 load_frag32_g(const char* rowbase, int k32) {
    union { i32x8 v; int4 h[2]; } u;
    u.h[0] = *(const int4*)(rowbase + k32);
    u.h[1] = *(const int4*)(rowbase + k32 + 16);
    return u.v;
}

// Stage one 64x128 fp8 tile (8KB): 2 iters of 256 threads x 16B.
__device__ __forceinline__ void stage8k(const char* gsrc, char* ldst, int tid) {
#pragma unroll
    for (int it = 0; it < 2; ++it) {
        int L   = it * 4096 + tid * 16;
        int row = L >> 7;
        int cb  = L & 127;
        int src = (row << 7) + (cb ^ ((row & 7) << 4));
        __builtin_amdgcn_global_load_lds(
            (const __attribute__((address_space(1))) void*)(gsrc + src),
            (__attribute__((address_space(3))) void*)(ldst + L), 16, 0, 0);
    }
}

// --------------------------- conversion kernel -----------------------------
__global__ void convert_kernel(const float* __restrict__ text,
                               const float* __restrict__ shape,
                               unsigned* __restrict__ Xt,
                               unsigned* __restrict__ Xm,
                               float* __restrict__ R,
                               float* __restrict__ out) {
    int idx = blockIdx.x * blockDim.x + threadIdx.x;     // 4 elements per thread
    if (idx >= B_ROWS * E_COLS / 4) return;
    if (idx < 4096) {                                    // zero R (2*8192 f32)
        float4 z; z.x = z.y = z.z = z.w = 0.f;
        ((float4*)R)[idx] = z;
    }
    if (idx == 0) *out = 0.f;
    int e = idx * 4;
    float4 t = *(const float4*)(text + e);
    unsigned tp = pk4_fp8(t.x, t.y, t.z, t.w);
    Xt[idx] = tp;
    int row = e >> 7;
    if (row & 1) {
        int col = e & 127;
        float4 s = *(const float4*)(shape + (row >> 1) * E_COLS + col);
        Xm[idx] = pk4_fp8(s.x, s.y, s.z, s.w);
    } else {
        Xm[idx] = tp;
    }
}

// --------------------------- fused GEMM + rowsum ---------------------------
// Block = (strip bm, split h in 0..7, layer l). Tiles k=0..7: t = t0 + 8k,
// bn = (bm+t)&127, t0 = (h==0)?8:h. h==0 also does the diagonal (from global).
// Redundant tile (h==0, bm>=64, k==7 i.e. t=64) gated to 0 (owned by bm-64).
__launch_bounds__(256, 3)
__global__ void gemm_rowsum_kernel(const unsigned char* __restrict__ Xt,
                                   const unsigned char* __restrict__ Xm,
                                   float* __restrict__ R) {
    const int bm = blockIdx.x, h = blockIdx.y, l = blockIdx.z;
    const char* gX = (const char*)(l ? Xm : Xt);

    __shared__ __align__(16) char bufs[3][2][64 * 128];  // 48KB ring of pairs
    const int tid = threadIdx.x;

    const int t0 = (h == 0) ? NH : h;
    const float g7 = (h == 0 && bm >= 64) ? 0.f : 1.f;   // gate for k==7

    const int lane = tid & 63;
    const int w  = tid >> 6;
    const int wr = w >> 1, wc = w & 1;
    const int rA0 = wr * 32 + (lane & 15);
    const int rB0 = wc * 32 + (lane & 15);
    const int k32 = (lane >> 4) * 32;            // byte offset of lane's K-slice

    // ---- prologue issue order: A frags (4), diag B (4, h==0), P0 (4), P1 (4)
    const char* Ag = gX + (size_t)bm * 8192;
    i32x8 afr[2];
    afr[0] = load_frag32_g(Ag + (size_t)rA0 * 128, k32);
    afr[1] = load_frag32_g(Ag + (size_t)(rA0 + 16) * 128, k32);

    i32x8 db0 = {}, db1 = {};
    if (h == 0) {
        db0 = load_frag32_g(Ag + (size_t)rB0 * 128, k32);
        db1 = load_frag32_g(Ag + (size_t)(rB0 + 16) * 128, k32);
    }

    stage8k(gX + (size_t)((bm + t0)     & 127) * 8192, bufs[0][0], tid);
    stage8k(gX + (size_t)((bm + t0 + 8) & 127) * 8192, bufs[0][1], tid);
    stage8k(gX + (size_t)((bm + t0 + 16) & 127) * 8192, bufs[1][0], tid);
    stage8k(gX + (size_t)((bm + t0 + 24) & 127) * 8192, bufs[1][1], tid);

    // A (+diag) landed; 8 pair-loads still in flight
    asm volatile("s_waitcnt vmcnt(8)" ::: "memory");

    float s_r[2][4] = {{0.f}};                   // persistent row partials [m][j]
    float sc[8][2];                              // deferred col partials

    // ---- diagonal tile (h==0): rows only ----
    if (h == 0) {
        f32x4 acc[2][2] = {};
        acc[0][0] = __builtin_amdgcn_mfma_scale_f32_16x16x128_f8f6f4(
            afr[0], db0, acc[0][0], 0, 0, 0, SCALE1, 0, SCALE1);
        acc[0][1] = __builtin_amdgcn_mfma_scale_f32_16x16x128_f8f6f4(
            afr[0], db1, acc[0][1], 0, 0, 0, SCALE1, 0, SCALE1);
        acc[1][0] = __builtin_amdgcn_mfma_scale_f32_16x16x128_f8f6f4(
            afr[1], db0, acc[1][0], 0, 0, 0, SCALE1, 0, SCALE1);
        acc[1][1] = __builtin_amdgcn_mfma_scale_f32_16x16x128_f8f6f4(
            afr[1], db1, acc[1][1], 0, 0, 0, SCALE1, 0, SCALE1);
#pragma unroll
        for (int m = 0; m < 2; ++m)
#pragma unroll
            for (int n = 0; n < 2; ++n)
#pragma unroll
                for (int j = 0; j < 4; ++j)
                    s_r[m][j] += __builtin_amdgcn_exp2f(acc[m][n][j]);
    }

    // ---- main loop: 4 pair-iterations, ONE barrier each, fully unrolled ----
#pragma unroll
    for (int p = 0; p < 4; ++p) {
        // wait: pair p landed (keep newer stages in flight)
        if (p < 3) { asm volatile("s_waitcnt vmcnt(4)" ::: "memory"); }
        else       { asm volatile("s_waitcnt vmcnt(0)" ::: "memory"); }
        __builtin_amdgcn_s_barrier();            // all waves' stage loads done
                                                 // + prior-iter reads done
        // stage pair p+2 into bank (p+2)%3 (freed: consumed at iter p-1)
        if (p + 2 < 4) {
            stage8k(gX + (size_t)((bm + t0 + 8 * (2 * p + 4)) & 127) * 8192,
                    bufs[(p + 2) % 3][0], tid);
            stage8k(gX + (size_t)((bm + t0 + 8 * (2 * p + 5)) & 127) * 8192,
                    bufs[(p + 2) % 3][1], tid);
        }

#pragma unroll
        for (int sub = 0; sub < 2; ++sub) {
            const int k = 2 * p + sub;           // tile index 0..7 (static)
            const char* lsrc = bufs[p % 3][sub];
            i32x8 bfr0 = load_frag32(lsrc, rB0, k32);
            i32x8 bfr1 = load_frag32(lsrc, rB0 + 16, k32);

            f32x4 acc[2][2] = {};
            __builtin_amdgcn_s_setprio(1);
            acc[0][0] = __builtin_amdgcn_mfma_scale_f32_16x16x128_f8f6f4(
                afr[0], bfr0, acc[0][0], 0, 0, 0, SCALE1, 0, SCALE1);
            acc[0][1] = __builtin_amdgcn_mfma_scale_f32_16x16x128_f8f6f4(
                afr[0], bfr1, acc[0][1], 0, 0, 0, SCALE1, 0, SCALE1);
            acc[1][0] = __builtin_amdgcn_mfma_scale_f32_16x16x128_f8f6f4(
                afr[1], bfr0, acc[1][0], 0, 0, 0, SCALE1, 0, SCALE1);
            acc[1][1] = __builtin_amdgcn_mfma_scale_f32_16x16x128_f8f6f4(
                afr[1], bfr1, acc[1][1], 0, 0, 0, SCALE1, 0, SCALE1);
            __builtin_amdgcn_s_setprio(0);

            const float g = (k == 7) ? g7 : 1.f;
            float c0 = 0.f, c1 = 0.f;
#pragma unroll
            for (int m = 0; m < 2; ++m)
#pragma unroll
                for (int j = 0; j < 4; ++j) {
                    float e0 = __builtin_amdgcn_exp2f(acc[m][0][j]) * g;
                    float e1 = __builtin_amdgcn_exp2f(acc[m][1][j]) * g;
                    s_r[m][j] += e0 + e1;
                    c0 += e0;
                    c1 += e1;
                }
            sc[k][0] = c0;                       // static index (unrolled)
            sc[k][1] = c1;
        }
        // my ds_reads of bank p%3 done before next iteration's barrier
        asm volatile("s_waitcnt lgkmcnt(0)" ::: "memory");
    }

    // ---- deferred column reductions + atomics (out of the sync loop) ----
#pragma unroll
    for (int k = 0; k < 8; ++k) {
        const int bn = (bm + t0 + 8 * k) & 127;
#pragma unroll
        for (int n = 0; n < 2; ++n) {
            float v = sc[k][n];
            v += __shfl_xor(v, 16, 64);
            v += __shfl_xor(v, 32, 64);
            if (lane < 16) {
                int gcol = bn * 64 + wc * 32 + n * 16 + lane;
                atomicAdd(&R[l * B_ROWS + gcol], EULER * v);
            }
        }
    }

    // ---- final row reduction (once per block) ----
#pragma unroll
    for (int m = 0; m < 2; ++m)
#pragma unroll
        for (int j = 0; j < 4; ++j) {
            float v = s_r[m][j];
            v += __shfl_xor(v, 1, 64);
            v += __shfl_xor(v, 2, 64);
            v += __shfl_xor(v, 4, 64);
            v += __shfl_xor(v, 8, 64);
            if ((lane & 15) == 0) {
                int grow = bm * 64 + wr * 32 + m * 16 + (lane >> 4) * 4 + j;
                atomicAdd(&R[l * B_ROWS + grow], EULER * v);
            }
        }
}

// --------------------------- finalize --------------------------------------
__global__ void finalize_kernel(const float* __restrict__ text,
                                const float* __restrict__ shape,
                                const float* __restrict__ R,
                                float* __restrict__ out) {
    const int tid = threadIdx.x;
    const int lane = tid & 63;
    const int w = tid >> 6;
    const float inv128 = 0.0078125f;
    float accum = 0.f;

    for (int task = blockIdx.x * 4 + w; task < 2 * P_PAIRS; task += 1024) {
        int l = task >> 12;
        int p = task & (P_PAIRS - 1);
        const float* a = text + (2 * p) * E_COLS;            // even row: text
        const float* b = l ? (shape + p * E_COLS) : (text + (2 * p + 1) * E_COLS);
        float2 av = *(const float2*)(a + lane * 2);
        float2 bv = *(const float2*)(b + lane * 2);
        float dii = av.x * av.x + av.y * av.y;
        float djj = bv.x * bv.x + bv.y * bv.y;
        float dij = av.x * bv.x + av.y * bv.y;
#pragma unroll
        for (int sh = 1; sh < 64; sh <<= 1) {
            dii += __shfl_xor(dii, sh, 64);
            djj += __shfl_xor(djj, sh, 64);
            dij += __shfl_xor(dij, sh, 64);
        }
        if (lane == 0) {
            float Dii = dii * inv128, Djj = djj * inv128, Dij = dij * inv128;
            float S = R[l * B_ROWS + 2 * p] + R[l * B_ROWS + 2 * p + 1]
                    - (__expf(1.f + Dii) + 2.f * __expf(1.f + Dij) + __expf(1.f + Djj));
            float J = __logf(S) - Dij;
            accum += 0.5f * J * J * (1.0f / (float)P_PAIRS);
        }
    }

    __shared__ float red[4];
    if (lane == 0) red[w] = accum;
    __syncthreads();
    if (tid == 0) atomicAdd(out, red[0] + red[1] + red[2] + red[3]);
}

// --------------------------- launch ----------------------------------------
extern "C" void kernel_launch(void* const* d_in, const int* in_sizes, int n_in,
                              void* d_out, int out_size, void* d_ws, size_t ws_size,
                              hipStream_t stream) {
    const float* text  = (const float*)d_in[0];
    const float* shape = (const float*)d_in[1];
    float* out = (float*)d_out;
    char* ws = (char*)d_ws;

    unsigned char* Xt = (unsigned char*)ws;
    unsigned char* Xm = (unsigned char*)(ws + 1u * 1024u * 1024u);
    float* R = (float*)(ws + 2u * 1024u * 1024u);

    convert_kernel<<<(B_ROWS * E_COLS / 4 + 255) / 256, 256, 0, stream>>>(
        text, shape, (unsigned*)Xt, (unsigned*)Xm, R, out);

    dim3 grid(NSTRIP, NH, 2);                    // 128 strips x 8 splits x 2 layers
    gemm_rowsum_kernel<<<grid, 256, 0, stream>>>(Xt, Xm, R);

    finalize_kernel<<<256, 256, 0, stream>>>(text, shape, R, out);
}

// Round 13
// 48.245 us; speedup vs baseline: 3.2030x; 1.0007x over previous
//
#include <hip/hip_runtime.h>
#include <hip/hip_bf16.h>

// ---------------------------------------------------------------------------
// Metric_Loss: two fused (X X^T/128 -> exp(1+.) -> row-sum) passes + pair combine.
// B=8192, E=128, P=4096.  Output: scalar f32 = metric_tt + metric_st.
//
// Round 13: occupancy-max. R8's measured-best body UNCHANGED (MX-fp8
// 16x16x128, 2-phase counted-vmcnt, NH=8, 16KB LDS) with launch_bounds
// (256,8): 2048 blocks = exactly 8/CU -> ALL blocks co-resident, 32 waves/CU
// (hw max), zero tail. R11/R12 established runtime ~ 1/resident-waves and
// occupancy > pipeline depth; this is the pure-occupancy lever.
//
// ws layout:
//   [0, 1MB)        Xt fp8    [8192][128]   scaled by sqrt(log2e/128)
//   [1MB, 2MB)      Xm fp8    [8192][128]   (mixed: even=text, odd=shape[r>>1])
//   [2MB, 2MB+64KB) R f32     [2][8192]     row sums of exp(1+D)
// ---------------------------------------------------------------------------

#define B_ROWS 8192
#define E_COLS 128
#define P_PAIRS 4096
#define NSTRIP 128              // 64-row strips
#define NH 8                    // h-splits per strip

using f32x4 = __attribute__((ext_vector_type(4))) float;
using i32x8 = __attribute__((ext_vector_type(8))) int;

// sqrt(log2(e)/128): MFMA yields acc = D*log2(e); exp(1+D) = e * exp2(acc)
#define BF_SCALE 0.106164482742544f
#define EULER    2.718281828459045f
#define SCALE1   0x7f            // E8M0 exponent 127 -> 2^0 (unit scale)

__device__ __forceinline__ unsigned pk4_fp8(float a, float b, float c, float d) {
    unsigned v = 0;
    v = __builtin_amdgcn_cvt_pk_fp8_f32(a * BF_SCALE, b * BF_SCALE, v, false);
    v = __builtin_amdgcn_cvt_pk_fp8_f32(c * BF_SCALE, d * BF_SCALE, v, true);
    return v;
}

__device__ __forceinline__ int lds_off(int row, int k0) {
    return (row << 7) + (k0 ^ ((row & 7) << 4));
}

// K=128 fragment from swizzled LDS: 32 contiguous fp8 at (row, k32).
__device__ __forceinline__ i32x8 load_frag32(const char* base, int row, int k32) {
    union { i32x8 v; int4 h[2]; } u;
    u.h[0] = *(const int4*)(base + lds_off(row, k32));
    u.h[1] = *(const int4*)(base + lds_off(row, k32 + 16));
    return u.v;
}

// Stage one 64x128 fp8 tile (8KB): 2 iters of 256 threads x 16B.
__device__ __forceinline__ void stage8k(const char* gsrc, char* ldst, int tid) {
#pragma unroll
    for (int it = 0; it < 2; ++it) {
        int L   = it * 4096 + tid * 16;
        int row = L >> 7;
        int cb  = L & 127;
        int src = (row << 7) + (cb ^ ((row & 7) << 4));
        __builtin_amdgcn_global_load_lds(
            (const __attribute__((address_space(1))) void*)(gsrc + src),
            (__attribute__((address_space(3))) void*)(ldst + L), 16, 0, 0);
    }
}

// --------------------------- conversion kernel -----------------------------
__global__ void convert_kernel(const float* __restrict__ text,
                               const float* __restrict__ shape,
                               unsigned* __restrict__ Xt,
                               unsigned* __restrict__ Xm,
                               float* __restrict__ R,
                               float* __restrict__ out) {
    int idx = blockIdx.x * blockDim.x + threadIdx.x;     // 4 elements per thread
    if (idx >= B_ROWS * E_COLS / 4) return;
    if (idx < 4096) {                                    // zero R (2*8192 f32)
        float4 z; z.x = z.y = z.z = z.w = 0.f;
        ((float4*)R)[idx] = z;
    }
    if (idx == 0) *out = 0.f;
    int e = idx * 4;
    float4 t = *(const float4*)(text + e);
    unsigned tp = pk4_fp8(t.x, t.y, t.z, t.w);
    Xt[idx] = tp;
    int row = e >> 7;
    if (row & 1) {
        int col = e & 127;
        float4 s = *(const float4*)(shape + (row >> 1) * E_COLS + col);
        Xm[idx] = pk4_fp8(s.x, s.y, s.z, s.w);
    } else {
        Xm[idx] = tp;
    }
}

// --------------------------- fused GEMM + rowsum (MX-fp8) ------------------
// Block = (strip bm in 0..127, split h in 0..7, layer l). Strip = 64 A-rows.
// Tiles (bm, bn=(bm+t)&127): t in {1..63} each unordered pair once; t==64
// gated bm<64 (h==0); t==0 diagonal (h==0, from buf0). Wave: 32x32 quadrant.
__launch_bounds__(256, 8)
__global__ void gemm_rowsum_kernel(const unsigned char* __restrict__ Xt,
                                   const unsigned char* __restrict__ Xm,
                                   float* __restrict__ R) {
    const int bm = blockIdx.x, h = blockIdx.y, l = blockIdx.z;
    const char* gX = (const char*)(l ? Xm : Xt);

    __shared__ __align__(16) char buf0[64 * 128];
    __shared__ __align__(16) char buf1[64 * 128];
    const int tid = threadIdx.x;

    const int t0 = (h == 0) ? NH : h;
    const int N  = (h == 0) ? (bm < 64 ? 8 : 7) : 8;     // off-diag tile count

    // ---- prologue: stage A -> buf0, first B -> buf1 ----
    stage8k(gX + (size_t)bm * 8192, buf0, tid);
    stage8k(gX + (size_t)((bm + t0) & 127) * 8192, buf1, tid);
    asm volatile("s_waitcnt vmcnt(2)" ::: "memory");     // A landed
    __builtin_amdgcn_s_barrier();

    const int lane = tid & 63;
    const int w  = tid >> 6;
    const int wr = w >> 1, wc = w & 1;
    const int rA0 = wr * 32 + (lane & 15);
    const int rB0 = wc * 32 + (lane & 15);
    const int k32 = (lane >> 4) * 32;            // byte offset of lane's K-slice

    // ---- hoist A fragments (2 m-frags, full K=128 each) ----
    i32x8 afr[2];
#pragma unroll
    for (int m = 0; m < 2; ++m)
        afr[m] = load_frag32(buf0, rA0 + m * 16, k32);

    float s_r[2][4] = {{0.f}};                   // persistent row partials [m][j]

    // ---- diagonal tile (h==0): B-frags also from buf0; rows only ----
    if (h == 0) {
        i32x8 bfr[2];
#pragma unroll
        for (int n = 0; n < 2; ++n)
            bfr[n] = load_frag32(buf0, rB0 + n * 16, k32);
        f32x4 acc[2][2] = {};
#pragma unroll
        for (int m = 0; m < 2; ++m)
#pragma unroll
            for (int n = 0; n < 2; ++n)
                acc[m][n] = __builtin_amdgcn_mfma_scale_f32_16x16x128_f8f6f4(
                    afr[m], bfr[n], acc[m][n], 0, 0, 0, SCALE1, 0, SCALE1);
#pragma unroll
        for (int m = 0; m < 2; ++m)
#pragma unroll
            for (int n = 0; n < 2; ++n)
#pragma unroll
                for (int j = 0; j < 4; ++j)
                    s_r[m][j] += __builtin_amdgcn_exp2f(acc[m][n][j]);
    }

    // ---- all buf0 reads done before it becomes a B buffer ----
    asm volatile("s_waitcnt lgkmcnt(0)" ::: "memory");
    __builtin_amdgcn_s_barrier();

    // ---- 2-phase pipelined loop over off-diagonal tiles ----
    int cur = 1;                                 // current B buffer: 1 -> buf1
    for (int idx = 0; idx < N; ++idx) {
        const bool hasnext = (idx + 1 < N);
        if (hasnext)
            stage8k(gX + (size_t)((bm + t0 + NH * (idx + 1)) & 127) * 8192,
                    cur ? buf0 : buf1, tid);

        if (hasnext) { asm volatile("s_waitcnt vmcnt(2)" ::: "memory"); }
        else         { asm volatile("s_waitcnt vmcnt(0)" ::: "memory"); }
        __builtin_amdgcn_s_barrier();            // cur buffer staged (all waves)

        const char* lsrc = cur ? buf1 : buf0;
        i32x8 bfr[2];
#pragma unroll
        for (int n = 0; n < 2; ++n)
            bfr[n] = load_frag32(lsrc, rB0 + n * 16, k32);
        f32x4 acc[2][2] = {};
#pragma unroll
        for (int m = 0; m < 2; ++m)
#pragma unroll
            for (int n = 0; n < 2; ++n)
                acc[m][n] = __builtin_amdgcn_mfma_scale_f32_16x16x128_f8f6f4(
                    afr[m], bfr[n], acc[m][n], 0, 0, 0, SCALE1, 0, SCALE1);

        asm volatile("s_waitcnt lgkmcnt(0)" ::: "memory");
        __builtin_amdgcn_s_barrier();            // cur reads done -> overwritable

        // ---- epilogue: rows -> regs, cols -> shuffle + atomics ----
        const int bn = (bm + t0 + NH * idx) & 127;
        float s_c[2] = {0.f, 0.f};
#pragma unroll
        for (int m = 0; m < 2; ++m)
#pragma unroll
            for (int n = 0; n < 2; ++n)
#pragma unroll
                for (int j = 0; j < 4; ++j) {
                    float e2 = __builtin_amdgcn_exp2f(acc[m][n][j]);
                    s_r[m][j] += e2;
                    s_c[n] += e2;
                }
#pragma unroll
        for (int n = 0; n < 2; ++n) {
            float v = s_c[n];
            v += __shfl_xor(v, 16, 64);
            v += __shfl_xor(v, 32, 64);
            if (lane < 16) {
                int gcol = bn * 64 + wc * 32 + n * 16 + lane;
                atomicAdd(&R[l * B_ROWS + gcol], EULER * v);
            }
        }
        cur ^= 1;
    }

    // ---- final row reduction (once per block) ----
#pragma unroll
    for (int m = 0; m < 2; ++m)
#pragma unroll
        for (int j = 0; j < 4; ++j) {
            float v = s_r[m][j];
            v += __shfl_xor(v, 1, 64);
            v += __shfl_xor(v, 2, 64);
            v += __shfl_xor(v, 4, 64);
            v += __shfl_xor(v, 8, 64);
            if ((lane & 15) == 0) {
                int grow = bm * 64 + wr * 32 + m * 16 + (lane >> 4) * 4 + j;
                atomicAdd(&R[l * B_ROWS + grow], EULER * v);
            }
        }
}

// --------------------------- finalize --------------------------------------
__global__ void finalize_kernel(const float* __restrict__ text,
                                const float* __restrict__ shape,
                                const float* __restrict__ R,
                                float* __restrict__ out) {
    const int tid = threadIdx.x;
    const int lane = tid & 63;
    const int w = tid >> 6;
    const float inv128 = 0.0078125f;
    float accum = 0.f;

    for (int task = blockIdx.x * 4 + w; task < 2 * P_PAIRS; task += 1024) {
        int l = task >> 12;
        int p = task & (P_PAIRS - 1);
        const float* a = text + (2 * p) * E_COLS;            // even row: text
        const float* b = l ? (shape + p * E_COLS) : (text + (2 * p + 1) * E_COLS);
        float2 av = *(const float2*)(a + lane * 2);
        float2 bv = *(const float2*)(b + lane * 2);
        float dii = av.x * av.x + av.y * av.y;
        float djj = bv.x * bv.x + bv.y * bv.y;
        float dij = av.x * bv.x + av.y * bv.y;
#pragma unroll
        for (int sh = 1; sh < 64; sh <<= 1) {
            dii += __shfl_xor(dii, sh, 64);
            djj += __shfl_xor(djj, sh, 64);
            dij += __shfl_xor(dij, sh, 64);
        }
        if (lane == 0) {
            float Dii = dii * inv128, Djj = djj * inv128, Dij = dij * inv128;
            float S = R[l * B_ROWS + 2 * p] + R[l * B_ROWS + 2 * p + 1]
                    - (__expf(1.f + Dii) + 2.f * __expf(1.f + Dij) + __expf(1.f + Djj));
            float J = __logf(S) - Dij;
            accum += 0.5f * J * J * (1.0f / (float)P_PAIRS);
        }
    }

    __shared__ float red[4];
    if (lane == 0) red[w] = accum;
    __syncthreads();
    if (tid == 0) atomicAdd(out, red[0] + red[1] + red[2] + red[3]);
}

// --------------------------- launch ----------------------------------------
extern "C" void kernel_launch(void* const* d_in, const int* in_sizes, int n_in,
                              void* d_out, int out_size, void* d_ws, size_t ws_size,
                              hipStream_t stream) {
    const float* text  = (const float*)d_in[0];
    const float* shape = (const float*)d_in[1];
    float* out = (float*)d_out;
    char* ws = (char*)d_ws;

    unsigned char* Xt = (unsigned char*)ws;
    unsigned char* Xm = (unsigned char*)(ws + 1u * 1024u * 1024u);
    float* R = (float*)(ws + 2u * 1024u * 1024u);

    convert_kernel<<<(B_ROWS * E_COLS / 4 + 255) / 256, 256, 0, stream>>>(
        text, shape, (unsigned*)Xt, (unsigned*)Xm, R, out);

    dim3 grid(NSTRIP, NH, 2);                    // 128 strips x 8 splits x 2 layers
    gemm_rowsum_kernel<<<grid, 256, 0, stream>>>(Xt, Xm, R);

    finalize_kernel<<<256, 256, 0, stream>>>(text, shape, R, out);
}